// Round 1
// 305.844 us; speedup vs baseline: 1.0059x; 1.0059x over previous
//
#include <hip/hip_runtime.h>
#include <stdint.h>

#define N_NODES 6144
#define LOG2E 1.44269504088896f

typedef float f32x4 __attribute__((ext_vector_type(4)));
typedef float f32x2 __attribute__((ext_vector_type(2)));
typedef short short8 __attribute__((ext_vector_type(8)));
typedef unsigned int uint32;
typedef unsigned long long uint64;

extern "C" __device__ float __ocml_native_exp2_f32(float);

// pack two floats -> two bf16 (round-half-up) in one u32: lo=a, hi=b
__device__ __forceinline__ unsigned int pack2bf(float a, float b) {
  unsigned int ua = __float_as_uint(a) + 0x8000u;
  unsigned int ub = __float_as_uint(b) + 0x8000u;
  return __builtin_amdgcn_perm(ub, ua, 0x07060302u);
}

// bit j of bits -> all-ones / all-zeros mask (v_bfe_i32: 1 instr)
__device__ __forceinline__ uint32 bitmask32(uint32 bits, int j) {
#if __has_builtin(__builtin_amdgcn_sbfe)
  return (uint32)__builtin_amdgcn_sbfe((int)bits, (uint32)j, 1u);
#else
  return (uint32)(((int)(bits << (31 - j))) >> 31);
#endif
}

// K0: bit-pack adjacency via wave ballot. Lane reads ONE int (coalesced
// 256B per wave instr), ballot packs 64 edges, one lane stores the u64.
__global__ __launch_bounds__(256) void k0_pack(const int* __restrict__ adj,
                                               uint64* __restrict__ mask64) {
  int t = threadIdx.x;
  int wid = t >> 6, lane = t & 63;
  int row = blockIdx.x * 4 + wid;
  const int* ar = adj + (size_t)row * N_NODES + lane;
  uint64* mr = mask64 + (size_t)row * 96;
  #pragma unroll 8
  for (int c = 0; c < 96; ++c) {
    int v = ar[c << 6];
    uint64 b = __ballot(v != 0);
    if (lane == (c & 63)) mr[c] = b;
  }
}

// K1: h = x*W (fp32). Features written in fragment-major layout
// hfF[h][kb32][frag][lane] (int4 per lane = exact MFMA B-fragment),
// so K2's loads are lane-contiguous. s_*2 = (h . a_*) * log2(e).
__global__ __launch_bounds__(256) void k1_feat(const float* __restrict__ x,
                                               const float* __restrict__ W,
                                               const float* __restrict__ a,
                                               unsigned short* __restrict__ hfF,
                                               float* __restrict__ s_src2,
                                               float* __restrict__ s_dst2) {
  __shared__ float xl[64][132];
  __shared__ float Wl[64][128];
  int t = threadIdx.x;
  int n0 = blockIdx.x * 64;
  for (int u = t; u < 2048; u += 256) {
    int row = u >> 5, c4 = (u & 31) << 2;
    *(float4*)&xl[row][c4] = *(const float4*)(x + (size_t)(n0 + row) * 128 + c4);
  }
  int cg = t & 31, c0 = cg << 2;
  int ng = t >> 5, nb = ng << 3;
  float acc[8][4] = {};
  for (int ic = 0; ic < 2; ++ic) {
    __syncthreads();
    for (int u = t; u < 2048; u += 256) {
      int ii = u >> 5, c4 = (u & 31) << 2;
      int hh = c4 >> 5, d0 = c4 & 31;
      *(float4*)&Wl[ii][c4] = *(const float4*)(W + hh * 4096 + (ic * 64 + ii) * 32 + d0);
    }
    __syncthreads();
    #pragma unroll 4
    for (int ii = 0; ii < 64; ++ii) {
      float4 wv = *(float4*)&Wl[ii][c0];
      int i = ic * 64 + ii;
      #pragma unroll
      for (int r = 0; r < 8; ++r) {
        float xv = xl[nb + r][i];
        acc[r][0] += xv * wv.x; acc[r][1] += xv * wv.y;
        acc[r][2] += xv * wv.z; acc[r][3] += xv * wv.w;
      }
    }
  }
  __syncthreads();
  unsigned short* tb = (unsigned short*)&xl[0][0];   // bf16 [128 cols][66 nodes]
  float* pb = &Wl[0][0];                             // float [2][64][33]
  int hh = c0 >> 5, d0 = c0 & 31;
  float4 adv = *(const float4*)(a + hh * 64 + d0);
  float4 asv = *(const float4*)(a + hh * 64 + 32 + d0);
  #pragma unroll
  for (int cc = 0; cc < 4; ++cc) {
    unsigned int* dst = (unsigned int*)(tb + (c0 + cc) * 66 + nb);
    #pragma unroll
    for (int p = 0; p < 4; ++p)
      dst[p] = pack2bf(acc[2 * p][cc], acc[2 * p + 1][cc]);
  }
  #pragma unroll
  for (int r = 0; r < 8; ++r) {
    float pd = acc[r][0] * adv.x + acc[r][1] * adv.y + acc[r][2] * adv.z + acc[r][3] * adv.w;
    float ps = acc[r][0] * asv.x + acc[r][1] * asv.y + acc[r][2] * asv.z + acc[r][3] * asv.w;
    pb[(nb + r) * 33 + cg] = pd;
    pb[2112 + (nb + r) * 33 + cg] = ps;
  }
  __syncthreads();
  // fragment-major store: chunk = (h, kb_local, f); lane holds
  // cols f*16+m of head h, nodes kb*32 + quad*8 .. +8  (int4 = 8 bf16)
  {
    #pragma unroll
    for (int p = 0; p < 4; ++p) {
      int chunk = (p << 2) + (t >> 6);
      int lane = t & 63, mm = lane & 15, qq = lane >> 4;
      int h2 = chunk >> 2, kbl = (chunk >> 1) & 1, ff = chunk & 1;
      const unsigned int* s32 = (const unsigned int*)(
          tb + (h2 * 32 + ff * 16 + mm) * 66 + kbl * 32 + (qq << 3));
      int4 v;
      v.x = s32[0]; v.y = s32[1]; v.z = s32[2]; v.w = s32[3];
      int kbg = (n0 >> 5) + kbl;
      *(int4*)(hfF + (size_t)(((h2 * 192 + kbg) * 2 + ff) * 64 + lane) * 8) = v;
    }
  }
  for (int task = t; task < 512; task += 256) {
    int n = task & 63, hz = task >> 6;
    int h = hz & 3, sdx = hz >> 2;
    const float* src = pb + sdx * 2112 + n * 33 + h * 8;
    float s = src[0] + src[1] + src[2] + src[3] + src[4] + src[5] + src[6] + src[7];
    float* out = sdx ? s_src2 : s_dst2;
    out[h * N_NODES + n0 + n] = s * LOG2E;
  }
}

// one m-tile k-step: weights in A-layout, 2 value-MFMAs + 1 z-MFMA (ones B).
// VALU-lean edge math: v_pk_add/v_pk_mul packed fp32, v_bfe_i32 sign-extend
// masks + AND (replaces cmp+cndmask), v_cvt_pk_bf16_f32 single-instr pack.
__device__ __forceinline__ void gat_tile(float ss, uint32 bits8,
                                         const f32x2 (&dv)[4], short8 b0, short8 b1,
                                         short8 ones, f32x4& a0, f32x4& a1, f32x4& az) {
  union { uint32 u4[4]; short8 v; } afr;
  f32x2 ss2;
  ss2[0] = ss; ss2[1] = ss;
  #pragma unroll
  for (int p = 0; p < 4; ++p) {
    f32x2 e = ss2 + dv[p];                   // v_pk_add_f32
    f32x2 e5 = e * 0.2f;                     // v_pk_mul_f32
    float lrl = fmaxf(e[0], e5[0]);          // leaky-relu (log2 domain)
    float lrh = fmaxf(e[1], e5[1]);
    float exl = __ocml_native_exp2_f32(lrl); // v_exp_f32
    float exh = __ocml_native_exp2_f32(lrh);
    uint32 wl = __float_as_uint(exl) & bitmask32(bits8, 2 * p);
    uint32 wh = __float_as_uint(exh) & bitmask32(bits8, 2 * p + 1);
    uint32 pk;
    asm("v_cvt_pk_bf16_f32 %0, %1, %2"
        : "=v"(pk)
        : "v"(__uint_as_float(wl)), "v"(__uint_as_float(wh)));
    afr.u4[p] = pk;
  }
  a0 = __builtin_amdgcn_mfma_f32_16x16x32_bf16(afr.v, b0, a0, 0, 0, 0);
  a1 = __builtin_amdgcn_mfma_f32_16x16x32_bf16(afr.v, b1, a1, 0, 0, 0);
  az = __builtin_amdgcn_mfma_f32_16x16x32_bf16(afr.v, ones, az, 0, 0, 0);
}

// one k-step across the 2 m-tiles (shared d/B operands)
__device__ __forceinline__ void step2(uint32 w0, uint32 w1,
                                      int sh, const float* sdp, int koff,
                                      int4 B0i, int4 B1i, short8 ones,
                                      float ss0, float ss1,
                                      f32x4& a00, f32x4& a01, f32x4& a10, f32x4& a11,
                                      f32x4& az0, f32x4& az1) {
  union { f32x4 q[2]; f32x2 d[4]; } du;
  du.q[0] = *(const f32x4*)(sdp + koff);
  du.q[1] = *(const f32x4*)(sdp + koff + 4);
  union { int4 i; short8 v; } b0u, b1u;
  b0u.i = B0i; b1u.i = B1i;
  gat_tile(ss0, (w0 >> sh), du.d, b0u.v, b1u.v, ones, a00, a01, az0);
  gat_tile(ss1, (w1 >> sh), du.d, b0u.v, b1u.v, ones, a10, a11, az1);
}

// K2: fused masked-softmax aggregate. Block = 4 waves = 4 heads x 32 rows
// (2 m-tiles) x k-slice 768 (split 8). ALL hot-loop global loads are
// lane-contiguous (hfF fragment-major: base + lane*16 = one 1KB coalesced
// request/instr); masks staged to LDS once (3 KB) and read as aligned
// b128 broadcasts.
__global__ __launch_bounds__(256, 4) void k2_attn(const uint32* __restrict__ maskw,
                                                  const unsigned short* __restrict__ hfF,
                                                  const float* __restrict__ s_src2,
                                                  const float* __restrict__ s_dst2,
                                                  float* __restrict__ Zpart,
                                                  float* __restrict__ part) {
  __shared__ float sd[4][768];    // 12 KB
  __shared__ uint32 mlds[32 * 24];  // 3 KB
  int t = threadIdx.x;
  int h = t >> 6, lane = t & 63, m = lane & 15, quad = lane >> 4;
  int sh = quad << 3;
  int bx = blockIdx.x;
  int slice = bx & 7, mg = bx >> 3;
  int i0 = mg << 5, kbase = slice * 768;   // 32 rows per block
  {
    const float4* g = (const float4*)s_dst2;
    float4* l = (float4*)sd;
    int kb4 = kbase >> 2;
    #pragma unroll
    for (int r = 0; r < 3; ++r) {
      int u = t + (r << 8);
      int hx = u / 192, uu = u - hx * 192;
      l[hx * 192 + uu] = g[hx * 1536 + kb4 + uu];
    }
  }
  for (int r = t; r < 768; r += 256) {
    int row = r / 24, w = r - row * 24;
    mlds[r] = maskw[(size_t)(i0 + row) * 192 + slice * 24 + w];
  }
  float ss0 = s_src2[h * N_NODES + i0 + m];
  float ss1 = s_src2[h * N_NODES + i0 + 16 + m];
  __syncthreads();

  // fragment base: [h][kb=slice*24 ..][frag][lane] — 1024 shorts per kb
  const unsigned short* hfb = hfF + (size_t)(h * 192 + slice * 24) * 1024 + lane * 8;
  const float* sdp = &sd[h][0] + sh;

  f32x4 a00 = {0,0,0,0}, a01 = {0,0,0,0};
  f32x4 a10 = {0,0,0,0}, a11 = {0,0,0,0};
  f32x4 az0 = {0,0,0,0}, az1 = {0,0,0,0};
  union { uint32 u[4]; short8 v; } ones;
  #pragma unroll
  for (int q = 0; q < 4; ++q) ones.u[q] = 0x3F803F80u;

  #pragma unroll 1
  for (int o = 0; o < 6; ++o) {
    const unsigned short* gb = hfb + o * 4096;   // 4 steps x 2 frags x 512
    int4 B00 = *(const int4*)(gb);
    int4 B01 = *(const int4*)(gb + 512);
    int4 B10 = *(const int4*)(gb + 1024);
    int4 B11 = *(const int4*)(gb + 1536);
    int4 B20 = *(const int4*)(gb + 2048);
    int4 B21 = *(const int4*)(gb + 2560);
    int4 B30 = *(const int4*)(gb + 3072);
    int4 B31 = *(const int4*)(gb + 3584);
    uint4 M0 = *(const uint4*)&mlds[m * 24 + (o << 2)];
    uint4 M1 = *(const uint4*)&mlds[(16 + m) * 24 + (o << 2)];
    __builtin_amdgcn_sched_barrier(0);
    int ko = o << 7;
    step2(M0.x, M1.x, sh, sdp, ko,      B00, B01, ones.v, ss0, ss1,
          a00, a01, a10, a11, az0, az1);
    step2(M0.y, M1.y, sh, sdp, ko + 32, B10, B11, ones.v, ss0, ss1,
          a00, a01, a10, a11, az0, az1);
    step2(M0.z, M1.z, sh, sdp, ko + 64, B20, B21, ones.v, ss0, ss1,
          a00, a01, a10, a11, az0, az1);
    step2(M0.w, M1.w, sh, sdp, ko + 96, B30, B31, ones.v, ss0, ss1,
          a00, a01, a10, a11, az0, az1);
  }

  // Z per-slice stores: ones-MFMA made every column hold the row sum
  if (m == 0) {
    float* zb = Zpart + (size_t)slice * 24576 + h * N_NODES + i0 + (quad << 2);
    #pragma unroll
    for (int r = 0; r < 4; ++r) {
      zb[r] = az0[r];
      zb[16 + r] = az1[r];
    }
  }
  // partial stores: part[slice][h][row][col]; D: col=lane&15, row=quad*4+reg
  float* pb = part + (size_t)slice * 786432 + (size_t)h * (N_NODES * 32) +
              (size_t)i0 * 32;
  #pragma unroll
  for (int r = 0; r < 4; ++r) {
    int row = (quad << 2) + r;
    pb[row * 32 + m] = a00[r];
    pb[row * 32 + 16 + m] = a01[r];
    pb[(16 + row) * 32 + m] = a10[r];
    pb[(16 + row) * 32 + 16 + m] = a11[r];
  }
}

// K3: out = sum_s part[s] / sum_s Z[s]
__global__ __launch_bounds__(256) void k3_final(const float* __restrict__ part,
                                                const float* __restrict__ Zpart,
                                                float* __restrict__ out) {
  unsigned int idx4 = blockIdx.x * 256 + threadIdx.x;   // float4 index
  unsigned int h = idx4 / 49152u;
  unsigned int i = (idx4 - h * 49152u) >> 3;
  float z = 0.f;
  #pragma unroll
  for (int s = 0; s < 8; ++s) z += Zpart[s * 24576u + h * N_NODES + i];
  f32x4 p = {0.f, 0.f, 0.f, 0.f};
  const f32x4* P = (const f32x4*)part;
  #pragma unroll
  for (int s = 0; s < 8; ++s) p += P[(size_t)s * 196608u + idx4];
  float rz = 1.0f / z;
  ((f32x4*)out)[idx4] = p * rz;
}

extern "C" void kernel_launch(void* const* d_in, const int* in_sizes, int n_in,
                              void* d_out, int out_size, void* d_ws, size_t ws_size,
                              hipStream_t stream) {
  const float* x = (const float*)d_in[0];
  const int* adj = (const int*)d_in[1];
  const float* W = (const float*)d_in[2];
  const float* a = (const float*)d_in[3];
  float* out = (float*)d_out;

  float* wsf = (float*)d_ws;
  unsigned short* hfF = (unsigned short*)wsf;       // 4*192*2*64*8 bf16 (1.5 MB)
  float* s_src2 = wsf + 393216;                     // 4*6144
  float* s_dst2 = s_src2 + 24576;                   // 4*6144
  float* part   = s_dst2 + 24576;                   // 8 slices * 786432 (24 MB)
  float* Zpart  = part + 8 * 786432;                // 8 slices * 24576
  uint64* mask64 = (uint64*)(Zpart + 8 * 24576);    // 6144*96 u64 (4.7 MB)

  hipLaunchKernelGGL(k0_pack, dim3(1536), dim3(256), 0, stream, adj, mask64);
  hipLaunchKernelGGL(k1_feat, dim3(96), dim3(256), 0, stream, x, W, a, hfF, s_src2, s_dst2);
  hipLaunchKernelGGL(k2_attn, dim3(1536), dim3(256), 0, stream,
                     (const uint32*)mask64, hfF, s_src2, s_dst2, Zpart, part);
  hipLaunchKernelGGL(k3_final, dim3(768), dim3(256), 0, stream, part, Zpart, out);
}

// Round 2
// 255.137 us; speedup vs baseline: 1.2059x; 1.1987x over previous
//
#include <hip/hip_runtime.h>
#include <stdint.h>

#define N_NODES 6144
#define LOG2E 1.44269504088896f

typedef float f32x4 __attribute__((ext_vector_type(4)));
typedef float f32x2 __attribute__((ext_vector_type(2)));
typedef short short8 __attribute__((ext_vector_type(8)));
typedef unsigned int uint32;
typedef unsigned long long uint64;

extern "C" __device__ float __ocml_native_exp2_f32(float);

// pack two floats -> two bf16 (round-half-up) in one u32: lo=a, hi=b
__device__ __forceinline__ unsigned int pack2bf(float a, float b) {
  unsigned int ua = __float_as_uint(a) + 0x8000u;
  unsigned int ub = __float_as_uint(b) + 0x8000u;
  return __builtin_amdgcn_perm(ub, ua, 0x07060302u);
}

// bit j of bits -> all-ones / all-zeros mask (v_bfe_i32: 1 instr)
__device__ __forceinline__ uint32 bitmask32(uint32 bits, int j) {
#if __has_builtin(__builtin_amdgcn_sbfe)
  return (uint32)__builtin_amdgcn_sbfe((int)bits, (uint32)j, 1u);
#else
  return (uint32)(((int)(bits << (31 - j))) >> 31);
#endif
}

// K1: h = x*W (fp32). Features written in fragment-major layout
// hfF[h][kb32][frag][lane] (int4 per lane = exact MFMA B-fragment),
// so K2's loads are lane-contiguous. s_*2 = (h . a_*) * log2(e).
__global__ __launch_bounds__(256) void k1_feat(const float* __restrict__ x,
                                               const float* __restrict__ W,
                                               const float* __restrict__ a,
                                               unsigned short* __restrict__ hfF,
                                               float* __restrict__ s_src2,
                                               float* __restrict__ s_dst2) {
  __shared__ float xl[64][132];
  __shared__ float Wl[64][128];
  int t = threadIdx.x;
  int n0 = blockIdx.x * 64;
  for (int u = t; u < 2048; u += 256) {
    int row = u >> 5, c4 = (u & 31) << 2;
    *(float4*)&xl[row][c4] = *(const float4*)(x + (size_t)(n0 + row) * 128 + c4);
  }
  int cg = t & 31, c0 = cg << 2;
  int ng = t >> 5, nb = ng << 3;
  float acc[8][4] = {};
  for (int ic = 0; ic < 2; ++ic) {
    __syncthreads();
    for (int u = t; u < 2048; u += 256) {
      int ii = u >> 5, c4 = (u & 31) << 2;
      int hh = c4 >> 5, d0 = c4 & 31;
      *(float4*)&Wl[ii][c4] = *(const float4*)(W + hh * 4096 + (ic * 64 + ii) * 32 + d0);
    }
    __syncthreads();
    #pragma unroll 4
    for (int ii = 0; ii < 64; ++ii) {
      float4 wv = *(float4*)&Wl[ii][c0];
      int i = ic * 64 + ii;
      #pragma unroll
      for (int r = 0; r < 8; ++r) {
        float xv = xl[nb + r][i];
        acc[r][0] += xv * wv.x; acc[r][1] += xv * wv.y;
        acc[r][2] += xv * wv.z; acc[r][3] += xv * wv.w;
      }
    }
  }
  __syncthreads();
  unsigned short* tb = (unsigned short*)&xl[0][0];   // bf16 [128 cols][66 nodes]
  float* pb = &Wl[0][0];                             // float [2][64][33]
  int hh = c0 >> 5, d0 = c0 & 31;
  float4 adv = *(const float4*)(a + hh * 64 + d0);
  float4 asv = *(const float4*)(a + hh * 64 + 32 + d0);
  #pragma unroll
  for (int cc = 0; cc < 4; ++cc) {
    unsigned int* dst = (unsigned int*)(tb + (c0 + cc) * 66 + nb);
    #pragma unroll
    for (int p = 0; p < 4; ++p)
      dst[p] = pack2bf(acc[2 * p][cc], acc[2 * p + 1][cc]);
  }
  #pragma unroll
  for (int r = 0; r < 8; ++r) {
    float pd = acc[r][0] * adv.x + acc[r][1] * adv.y + acc[r][2] * adv.z + acc[r][3] * adv.w;
    float ps = acc[r][0] * asv.x + acc[r][1] * asv.y + acc[r][2] * asv.z + acc[r][3] * asv.w;
    pb[(nb + r) * 33 + cg] = pd;
    pb[2112 + (nb + r) * 33 + cg] = ps;
  }
  __syncthreads();
  // fragment-major store: chunk = (h, kb_local, f); lane holds
  // cols f*16+m of head h, nodes kb*32 + quad*8 .. +8  (int4 = 8 bf16)
  {
    #pragma unroll
    for (int p = 0; p < 4; ++p) {
      int chunk = (p << 2) + (t >> 6);
      int lane = t & 63, mm = lane & 15, qq = lane >> 4;
      int h2 = chunk >> 2, kbl = (chunk >> 1) & 1, ff = chunk & 1;
      const unsigned int* s32 = (const unsigned int*)(
          tb + (h2 * 32 + ff * 16 + mm) * 66 + kbl * 32 + (qq << 3));
      int4 v;
      v.x = s32[0]; v.y = s32[1]; v.z = s32[2]; v.w = s32[3];
      int kbg = (n0 >> 5) + kbl;
      *(int4*)(hfF + (size_t)(((h2 * 192 + kbg) * 2 + ff) * 64 + lane) * 8) = v;
    }
  }
  for (int task = t; task < 512; task += 256) {
    int n = task & 63, hz = task >> 6;
    int h = hz & 3, sdx = hz >> 2;
    const float* src = pb + sdx * 2112 + n * 33 + h * 8;
    float s = src[0] + src[1] + src[2] + src[3] + src[4] + src[5] + src[6] + src[7];
    float* out = sdx ? s_src2 : s_dst2;
    out[h * N_NODES + n0 + n] = s * LOG2E;
  }
}

// one m-tile k-step: weights in A-layout, 2 value-MFMAs + 1 z-MFMA (ones B).
// VALU-lean edge math: v_pk_add/v_pk_mul packed fp32, v_bfe_i32 sign-extend
// masks + AND (replaces cmp+cndmask), v_cvt_pk_bf16_f32 single-instr pack.
__device__ __forceinline__ void gat_tile(float ss, uint32 bits8,
                                         const f32x2 (&dv)[4], short8 b0, short8 b1,
                                         short8 ones, f32x4& a0, f32x4& a1, f32x4& az) {
  union { uint32 u4[4]; short8 v; } afr;
  f32x2 ss2;
  ss2[0] = ss; ss2[1] = ss;
  #pragma unroll
  for (int p = 0; p < 4; ++p) {
    f32x2 e = ss2 + dv[p];                   // v_pk_add_f32
    f32x2 e5 = e * 0.2f;                     // v_pk_mul_f32
    float lrl = fmaxf(e[0], e5[0]);          // leaky-relu (log2 domain)
    float lrh = fmaxf(e[1], e5[1]);
    float exl = __ocml_native_exp2_f32(lrl); // v_exp_f32
    float exh = __ocml_native_exp2_f32(lrh);
    uint32 wl = __float_as_uint(exl) & bitmask32(bits8, 2 * p);
    uint32 wh = __float_as_uint(exh) & bitmask32(bits8, 2 * p + 1);
    uint32 pk;
    asm("v_cvt_pk_bf16_f32 %0, %1, %2"
        : "=v"(pk)
        : "v"(__uint_as_float(wl)), "v"(__uint_as_float(wh)));
    afr.u4[p] = pk;
  }
  a0 = __builtin_amdgcn_mfma_f32_16x16x32_bf16(afr.v, b0, a0, 0, 0, 0);
  a1 = __builtin_amdgcn_mfma_f32_16x16x32_bf16(afr.v, b1, a1, 0, 0, 0);
  az = __builtin_amdgcn_mfma_f32_16x16x32_bf16(afr.v, ones, az, 0, 0, 0);
}

// one k-step across the 2 m-tiles (shared d/B operands)
__device__ __forceinline__ void step2(uint32 w0, uint32 w1,
                                      int sh, const float* sdp, int koff,
                                      int4 B0i, int4 B1i, short8 ones,
                                      float ss0, float ss1,
                                      f32x4& a00, f32x4& a01, f32x4& a10, f32x4& a11,
                                      f32x4& az0, f32x4& az1) {
  union { f32x4 q[2]; f32x2 d[4]; } du;
  du.q[0] = *(const f32x4*)(sdp + koff);
  du.q[1] = *(const f32x4*)(sdp + koff + 4);
  union { int4 i; short8 v; } b0u, b1u;
  b0u.i = B0i; b1u.i = B1i;
  gat_tile(ss0, (w0 >> sh), du.d, b0u.v, b1u.v, ones, a00, a01, az0);
  gat_tile(ss1, (w1 >> sh), du.d, b0u.v, b1u.v, ones, a10, a11, az1);
}

// K2: fused masked-softmax aggregate, now self-packing the adjacency.
// Block = 4 waves = 4 heads x 32 rows (2 m-tiles) x k-slice 1536 (split 4).
// Per o-iter (128 cols): B-frag loads (L2-resident hfF), then 16 coalesced
// 256B adj loads for o+1 (HBM stream hides under this iter's edge-math +
// MFMAs), compute, then ballot-pack -> double-buffered 1KB LDS mask buf,
// one barrier. This overlaps the mandatory 151MB adj read (was K0's ~25us
// serial BW time) with K2's VALU time.
__global__ __launch_bounds__(256, 3) void k2_attn(const int* __restrict__ adj,
                                                  const unsigned short* __restrict__ hfF,
                                                  const float* __restrict__ s_src2,
                                                  const float* __restrict__ s_dst2,
                                                  float* __restrict__ Zpart,
                                                  float* __restrict__ part) {
  __shared__ float sd[4][1536];       // 24 KB
  __shared__ uint32 mlds[2][32][4];   // 1 KB double-buffered o-chunk masks
  int t = threadIdx.x;
  int h = t >> 6, lane = t & 63, m = lane & 15, quad = lane >> 4;
  int sh = quad << 3;
  int bx = blockIdx.x;
  int slice = bx & 3, mg = bx >> 2;
  int i0 = mg << 5, kbase = slice * 1536;   // 32 rows, 1536 k per block
  // stage s_dst slice: 4 heads x 1536 floats = 1536 float4
  {
    const float4* g = (const float4*)s_dst2;
    float4* l = (float4*)sd;
    int kb4 = slice * 384;
    #pragma unroll
    for (int r = 0; r < 6; ++r) {
      int u = t + (r << 8);
      int hx = u / 384, uu = u - hx * 384;
      l[hx * 384 + uu] = g[hx * 1536 + kb4 + uu];
    }
  }
  // adj tile base for this wave's 8 rows (wave wid == h)
  const int* arow = adj + (size_t)(i0 + (h << 3)) * N_NODES + kbase + lane;
  // prologue: pack masks for o=0
  {
    #pragma unroll
    for (int r = 0; r < 16; ++r) {
      int v = arow[(r >> 1) * N_NODES + ((r & 1) << 6)];
      uint64 b = __ballot(v != 0);
      if (lane == r)
        *(uint64*)&mlds[0][(h << 3) + (r >> 1)][(r & 1) << 1] = b;
    }
  }
  float ss0 = s_src2[h * N_NODES + i0 + m];
  float ss1 = s_src2[h * N_NODES + i0 + 16 + m];
  __syncthreads();

  // fragment base: [h][kb=slice*48 ..][frag][lane] — 1024 shorts per kb
  const unsigned short* hfb = hfF + (size_t)(h * 192 + slice * 48) * 1024 + lane * 8;
  const float* sdp = &sd[h][0] + sh;

  f32x4 a00 = {0,0,0,0}, a01 = {0,0,0,0};
  f32x4 a10 = {0,0,0,0}, a11 = {0,0,0,0};
  f32x4 az0 = {0,0,0,0}, az1 = {0,0,0,0};
  union { uint32 u[4]; short8 v; } ones;
  #pragma unroll
  for (int q = 0; q < 4; ++q) ones.u[q] = 0x3F803F80u;

  #pragma unroll 1
  for (int o = 0; o < 12; ++o) {
    int cur = o & 1, nxt = cur ^ 1;
    // B-fragment loads FIRST (their waitcnt must not drain adj prefetch)
    const unsigned short* gb = hfb + o * 4096;   // 4 steps x 2 frags x 512
    int4 B00 = *(const int4*)(gb);
    int4 B01 = *(const int4*)(gb + 512);
    int4 B10 = *(const int4*)(gb + 1024);
    int4 B11 = *(const int4*)(gb + 1536);
    int4 B20 = *(const int4*)(gb + 2048);
    int4 B21 = *(const int4*)(gb + 2560);
    int4 B30 = *(const int4*)(gb + 3072);
    int4 B31 = *(const int4*)(gb + 3584);
    // adj prefetch for o+1: 16 x 256B coalesced wave loads
    int pv[16];
    if (o < 11) {
      const int* ap = arow + ((o + 1) << 7);
      #pragma unroll
      for (int r = 0; r < 16; ++r)
        pv[r] = ap[(r >> 1) * N_NODES + ((r & 1) << 6)];
    }
    uint4 M0 = *(const uint4*)&mlds[cur][m][0];
    uint4 M1 = *(const uint4*)&mlds[cur][16 + m][0];
    __builtin_amdgcn_sched_barrier(0);
    int ko = o << 7;
    step2(M0.x, M1.x, sh, sdp, ko,      B00, B01, ones.v, ss0, ss1,
          a00, a01, a10, a11, az0, az1);
    step2(M0.y, M1.y, sh, sdp, ko + 32, B10, B11, ones.v, ss0, ss1,
          a00, a01, a10, a11, az0, az1);
    step2(M0.z, M1.z, sh, sdp, ko + 64, B20, B21, ones.v, ss0, ss1,
          a00, a01, a10, a11, az0, az1);
    step2(M0.w, M1.w, sh, sdp, ko + 96, B30, B31, ones.v, ss0, ss1,
          a00, a01, a10, a11, az0, az1);
    __builtin_amdgcn_sched_barrier(0);
    if (o < 11) {
      #pragma unroll
      for (int r = 0; r < 16; ++r) {
        uint64 b = __ballot(pv[r] != 0);
        if (lane == r)
          *(uint64*)&mlds[nxt][(h << 3) + (r >> 1)][(r & 1) << 1] = b;
      }
    }
    __syncthreads();
  }

  // Z per-slice stores: ones-MFMA made every column hold the row sum
  if (m == 0) {
    float* zb = Zpart + (size_t)slice * 24576 + h * N_NODES + i0 + (quad << 2);
    #pragma unroll
    for (int r = 0; r < 4; ++r) {
      zb[r] = az0[r];
      zb[16 + r] = az1[r];
    }
  }
  // partial stores: part[slice][h][row][col]; D: col=lane&15, row=quad*4+reg
  float* pb = part + (size_t)slice * 786432 + (size_t)h * (N_NODES * 32) +
              (size_t)i0 * 32;
  #pragma unroll
  for (int r = 0; r < 4; ++r) {
    int row = (quad << 2) + r;
    pb[row * 32 + m] = a00[r];
    pb[row * 32 + 16 + m] = a01[r];
    pb[(16 + row) * 32 + m] = a10[r];
    pb[(16 + row) * 32 + 16 + m] = a11[r];
  }
}

// K3: out = sum_s part[s] / sum_s Z[s]   (4 slices)
__global__ __launch_bounds__(256) void k3_final(const float* __restrict__ part,
                                                const float* __restrict__ Zpart,
                                                float* __restrict__ out) {
  unsigned int idx4 = blockIdx.x * 256 + threadIdx.x;   // float4 index
  unsigned int h = idx4 / 49152u;
  unsigned int i = (idx4 - h * 49152u) >> 3;
  float z = 0.f;
  #pragma unroll
  for (int s = 0; s < 4; ++s) z += Zpart[s * 24576u + h * N_NODES + i];
  f32x4 p = {0.f, 0.f, 0.f, 0.f};
  const f32x4* P = (const f32x4*)part;
  #pragma unroll
  for (int s = 0; s < 4; ++s) p += P[(size_t)s * 196608u + idx4];
  float rz = 1.0f / z;
  ((f32x4*)out)[idx4] = p * rz;
}

extern "C" void kernel_launch(void* const* d_in, const int* in_sizes, int n_in,
                              void* d_out, int out_size, void* d_ws, size_t ws_size,
                              hipStream_t stream) {
  const float* x = (const float*)d_in[0];
  const int* adj = (const int*)d_in[1];
  const float* W = (const float*)d_in[2];
  const float* a = (const float*)d_in[3];
  float* out = (float*)d_out;

  float* wsf = (float*)d_ws;
  unsigned short* hfF = (unsigned short*)wsf;       // 4*192*2*64*8 bf16 (1.5 MB)
  float* s_src2 = wsf + 393216;                     // 4*6144
  float* s_dst2 = s_src2 + 24576;                   // 4*6144
  float* part   = s_dst2 + 24576;                   // 4 slices * 786432 (12 MB)
  float* Zpart  = part + 4 * 786432;                // 4 slices * 24576

  hipLaunchKernelGGL(k1_feat, dim3(96), dim3(256), 0, stream, x, W, a, hfF, s_src2, s_dst2);
  hipLaunchKernelGGL(k2_attn, dim3(768), dim3(256), 0, stream,
                     adj, hfF, s_src2, s_dst2, Zpart, part);
  hipLaunchKernelGGL(k3_final, dim3(768), dim3(256), 0, stream, part, Zpart, out);
}

// Round 4
// 247.725 us; speedup vs baseline: 1.2419x; 1.0299x over previous
//
#include <hip/hip_runtime.h>
#include <stdint.h>

#define N_NODES 6144
#define LOG2E 1.44269504088896f

typedef float f32x4 __attribute__((ext_vector_type(4)));
typedef float f32x2 __attribute__((ext_vector_type(2)));
typedef short short8 __attribute__((ext_vector_type(8)));
typedef unsigned int uint32;
typedef unsigned long long uint64;

extern "C" __device__ float __ocml_native_exp2_f32(float);

// bit j of bits -> all-ones / all-zeros mask (v_bfe_i32: 1 instr)
__device__ __forceinline__ uint32 bitmask32(uint32 bits, int j) {
#if __has_builtin(__builtin_amdgcn_sbfe)
  return (uint32)__builtin_amdgcn_sbfe((int)bits, (uint32)j, 1u);
#else
  return (uint32)(((int)(bits << (31 - j))) >> 31);
#endif
}

// K1: h = x*W (fp32), re-sharded to 768 blocks x 8 nodes (3 blocks/CU, all
// CUs busy — old 96-block version ran 37% of CUs at 1 wave/SIMD). Lane map
// r=t&7, cg=t>>3 makes each wave's W read one contiguous 128B row W[h][i][:]
// per k-step (64KB W per block, no intra-block redundancy). i-accumulation
// stays sequential 0..127 with round-half-up bf16 -> hfF bit-identical to
// the verified layout. s_*2 via 8-lane shuffle tree (association-only diff).
__global__ __launch_bounds__(256) void k1_feat(const float* __restrict__ x,
                                               const float* __restrict__ W,
                                               const float* __restrict__ a,
                                               unsigned short* __restrict__ hfF,
                                               float* __restrict__ s_src2,
                                               float* __restrict__ s_dst2) {
  __shared__ float xA[8][132];             // 4.2 KB
  __shared__ unsigned short tbp[128][12];  // 3 KB: [col][node] bf16
  int t = threadIdx.x;
  int bx = blockIdx.x;
  int n0 = bx << 3;
  {
    int row = t >> 5, c4 = (t & 31) << 2;
    *(float4*)&xA[row][c4] = *(const float4*)(x + (size_t)(n0 + row) * 128 + c4);
  }
  __syncthreads();
  int r = t & 7, cgA = t >> 3;             // cgA 0..31; wave w == head w
  int hh = cgA >> 3, d0 = (cgA & 7) << 2;
  const float* wp = W + hh * 4096 + d0;
  float ac0 = 0.f, ac1 = 0.f, ac2 = 0.f, ac3 = 0.f;
  #pragma unroll 8
  for (int i = 0; i < 128; ++i) {
    float xv = xA[r][i];
    float4 wv = *(const float4*)(wp + (i << 5));
    ac0 += xv * wv.x; ac1 += xv * wv.y;
    ac2 += xv * wv.z; ac3 += xv * wv.w;
  }
  int c0 = cgA << 2;                       // == hh*32 + d0
  tbp[c0 + 0][r] = (unsigned short)((__float_as_uint(ac0) + 0x8000u) >> 16);
  tbp[c0 + 1][r] = (unsigned short)((__float_as_uint(ac1) + 0x8000u) >> 16);
  tbp[c0 + 2][r] = (unsigned short)((__float_as_uint(ac2) + 0x8000u) >> 16);
  tbp[c0 + 3][r] = (unsigned short)((__float_as_uint(ac3) + 0x8000u) >> 16);
  float4 adv = *(const float4*)(a + hh * 64 + d0);
  float4 asv = *(const float4*)(a + hh * 64 + 32 + d0);
  float pd = ac0 * adv.x + ac1 * adv.y + ac2 * adv.z + ac3 * adv.w;
  float ps = ac0 * asv.x + ac1 * asv.y + ac2 * asv.z + ac3 * asv.w;
  // reduce over the 8 col-groups: lanes r + j*8 within the wave
  pd += __shfl_xor(pd, 8); pd += __shfl_xor(pd, 16); pd += __shfl_xor(pd, 32);
  ps += __shfl_xor(ps, 8); ps += __shfl_xor(ps, 16); ps += __shfl_xor(ps, 32);
  if (((t & 63) >> 3) == 0) {
    s_dst2[hh * N_NODES + n0 + r] = pd * LOG2E;
    s_src2[hh * N_NODES + n0 + r] = ps * LOG2E;
  }
  __syncthreads();
  if (t < 128) {   // fragment-major hfF store: this block fills quad qq of kb
    int h2 = t >> 5, ff = (t >> 4) & 1, mm = t & 15;
    const uint32* s32 = (const uint32*)&tbp[t][0];
    int4 v;
    v.x = s32[0]; v.y = s32[1]; v.z = s32[2]; v.w = s32[3];
    int kb = bx >> 2, qq = bx & 3;
    *(int4*)(hfF + (size_t)(((h2 * 192 + kb) * 2 + ff) * 64 + qq * 16 + mm) * 8) = v;
  }
}

// one m-tile k-step: weights in A-layout, 2 value-MFMAs + 1 z-MFMA (ones B).
// VALU-lean edge math: v_pk_add/v_pk_mul packed fp32, v_bfe_i32 sign-extend
// masks + AND (replaces cmp+cndmask), v_cvt_pk_bf16_f32 single-instr pack.
__device__ __forceinline__ void gat_tile(float ss, uint32 bits8,
                                         const f32x2 (&dv)[4], short8 b0, short8 b1,
                                         short8 ones, f32x4& a0, f32x4& a1, f32x4& az) {
  union { uint32 u4[4]; short8 v; } afr;
  f32x2 ss2;
  ss2[0] = ss; ss2[1] = ss;
  #pragma unroll
  for (int p = 0; p < 4; ++p) {
    f32x2 e = ss2 + dv[p];                   // v_pk_add_f32
    f32x2 e5 = e * 0.2f;                     // v_pk_mul_f32
    float lrl = fmaxf(e[0], e5[0]);          // leaky-relu (log2 domain)
    float lrh = fmaxf(e[1], e5[1]);
    float exl = __ocml_native_exp2_f32(lrl); // v_exp_f32
    float exh = __ocml_native_exp2_f32(lrh);
    uint32 wl = __float_as_uint(exl) & bitmask32(bits8, 2 * p);
    uint32 wh = __float_as_uint(exh) & bitmask32(bits8, 2 * p + 1);
    uint32 pk;
    asm("v_cvt_pk_bf16_f32 %0, %1, %2"
        : "=v"(pk)
        : "v"(__uint_as_float(wl)), "v"(__uint_as_float(wh)));
    afr.u4[p] = pk;
  }
  a0 = __builtin_amdgcn_mfma_f32_16x16x32_bf16(afr.v, b0, a0, 0, 0, 0);
  a1 = __builtin_amdgcn_mfma_f32_16x16x32_bf16(afr.v, b1, a1, 0, 0, 0);
  az = __builtin_amdgcn_mfma_f32_16x16x32_bf16(afr.v, ones, az, 0, 0, 0);
}

// one k-step across the 2 m-tiles (shared d/B operands)
__device__ __forceinline__ void step2(uint32 w0, uint32 w1,
                                      int sh, const float* sdp, int koff,
                                      int4 B0i, int4 B1i, short8 ones,
                                      float ss0, float ss1,
                                      f32x4& a00, f32x4& a01, f32x4& a10, f32x4& a11,
                                      f32x4& az0, f32x4& az1) {
  union { f32x4 q[2]; f32x2 d[4]; } du;
  du.q[0] = *(const f32x4*)(sdp + koff);
  du.q[1] = *(const f32x4*)(sdp + koff + 4);
  union { int4 i; short8 v; } b0u, b1u;
  b0u.i = B0i; b1u.i = B1i;
  gat_tile(ss0, (w0 >> sh), du.d, b0u.v, b1u.v, ones, a00, a01, az0);
  gat_tile(ss1, (w1 >> sh), du.d, b0u.v, b1u.v, ones, a10, a11, az1);
}

// K2: fused masked-softmax aggregate, self-packing the adjacency.
// Block = 4 waves = 4 heads x 32 rows (2 m-tiles) x k-slice 1536 (split 4).
// o=0 adjacency loads are hoisted to the FIRST instructions so their HBM
// latency hides under the s_dst staging; per o-iter, next chunk's 16
// coalesced 256B adj loads stream under this iter's edge-math + MFMAs.
__global__ __launch_bounds__(256, 3) void k2_attn(const int* __restrict__ adj,
                                                  const unsigned short* __restrict__ hfF,
                                                  const float* __restrict__ s_src2,
                                                  const float* __restrict__ s_dst2,
                                                  float* __restrict__ Zpart,
                                                  float* __restrict__ part) {
  __shared__ float sd[4][1536];       // 24 KB
  __shared__ uint32 mlds[2][32][4];   // 1 KB double-buffered o-chunk masks
  int t = threadIdx.x;
  int h = t >> 6, lane = t & 63, m = lane & 15, quad = lane >> 4;
  int sh = quad << 3;
  int bx = blockIdx.x;
  int slice = bx & 3, mg = bx >> 2;
  int i0 = mg << 5, kbase = slice * 1536;   // 32 rows, 1536 k per block

  // o=0 adjacency loads FIRST (latency hides under staging below)
  const int* arow = adj + (size_t)(i0 + (h << 3)) * N_NODES + kbase + lane;
  int av[16];
  #pragma unroll
  for (int r = 0; r < 16; ++r)
    av[r] = arow[(r >> 1) * N_NODES + ((r & 1) << 6)];

  // stage s_dst slice: 4 heads x 1536 floats = 1536 float4
  {
    const float4* g = (const float4*)s_dst2;
    float4* l = (float4*)sd;
    int kb4 = slice * 384;
    #pragma unroll
    for (int r = 0; r < 6; ++r) {
      int u = t + (r << 8);
      int hx = u / 384, uu = u - hx * 384;
      l[hx * 384 + uu] = g[hx * 1536 + kb4 + uu];
    }
  }
  float ss0 = s_src2[h * N_NODES + i0 + m];
  float ss1 = s_src2[h * N_NODES + i0 + 16 + m];
  // o=0 ballot pack
  #pragma unroll
  for (int r = 0; r < 16; ++r) {
    uint64 b = __ballot(av[r] != 0);
    if (lane == r)
      *(uint64*)&mlds[0][(h << 3) + (r >> 1)][(r & 1) << 1] = b;
  }
  __syncthreads();

  // fragment base: [h][kb=slice*48 ..][frag][lane] — 1024 shorts per kb
  const unsigned short* hfb = hfF + (size_t)(h * 192 + slice * 48) * 1024 + lane * 8;
  const float* sdp = &sd[h][0] + sh;

  f32x4 a00 = {0,0,0,0}, a01 = {0,0,0,0};
  f32x4 a10 = {0,0,0,0}, a11 = {0,0,0,0};
  f32x4 az0 = {0,0,0,0}, az1 = {0,0,0,0};
  union { uint32 u[4]; short8 v; } ones;
  #pragma unroll
  for (int q = 0; q < 4; ++q) ones.u[q] = 0x3F803F80u;

  #pragma unroll 1
  for (int o = 0; o < 12; ++o) {
    int cur = o & 1, nxt = cur ^ 1;
    // B-fragment loads FIRST (their waitcnt must not drain adj prefetch)
    const unsigned short* gb = hfb + o * 4096;   // 4 steps x 2 frags x 512
    int4 B00 = *(const int4*)(gb);
    int4 B01 = *(const int4*)(gb + 512);
    int4 B10 = *(const int4*)(gb + 1024);
    int4 B11 = *(const int4*)(gb + 1536);
    int4 B20 = *(const int4*)(gb + 2048);
    int4 B21 = *(const int4*)(gb + 2560);
    int4 B30 = *(const int4*)(gb + 3072);
    int4 B31 = *(const int4*)(gb + 3584);
    // adj prefetch for o+1: 16 x 256B coalesced wave loads
    int pv[16];
    if (o < 11) {
      const int* ap = arow + ((o + 1) << 7);
      #pragma unroll
      for (int r = 0; r < 16; ++r)
        pv[r] = ap[(r >> 1) * N_NODES + ((r & 1) << 6)];
    }
    uint4 M0 = *(const uint4*)&mlds[cur][m][0];
    uint4 M1 = *(const uint4*)&mlds[cur][16 + m][0];
    __builtin_amdgcn_sched_barrier(0);
    int ko = o << 7;
    step2(M0.x, M1.x, sh, sdp, ko,      B00, B01, ones.v, ss0, ss1,
          a00, a01, a10, a11, az0, az1);
    step2(M0.y, M1.y, sh, sdp, ko + 32, B10, B11, ones.v, ss0, ss1,
          a00, a01, a10, a11, az0, az1);
    step2(M0.z, M1.z, sh, sdp, ko + 64, B20, B21, ones.v, ss0, ss1,
          a00, a01, a10, a11, az0, az1);
    step2(M0.w, M1.w, sh, sdp, ko + 96, B30, B31, ones.v, ss0, ss1,
          a00, a01, a10, a11, az0, az1);
    __builtin_amdgcn_sched_barrier(0);
    if (o < 11) {
      #pragma unroll
      for (int r = 0; r < 16; ++r) {
        uint64 b = __ballot(pv[r] != 0);
        if (lane == r)
          *(uint64*)&mlds[nxt][(h << 3) + (r >> 1)][(r & 1) << 1] = b;
      }
    }
    __syncthreads();
  }

  // Z per-slice stores: ones-MFMA made every column hold the row sum
  if (m == 0) {
    float* zb = Zpart + (size_t)slice * 24576 + h * N_NODES + i0 + (quad << 2);
    #pragma unroll
    for (int r = 0; r < 4; ++r) {
      zb[r] = az0[r];
      zb[16 + r] = az1[r];
    }
  }
  // partial stores: part[slice][h][row][col]; D: col=lane&15, row=quad*4+reg
  float* pb = part + (size_t)slice * 786432 + (size_t)h * (N_NODES * 32) +
              (size_t)i0 * 32;
  #pragma unroll
  for (int r = 0; r < 4; ++r) {
    int row = (quad << 2) + r;
    pb[row * 32 + m] = a00[r];
    pb[row * 32 + 16 + m] = a01[r];
    pb[(16 + row) * 32 + m] = a10[r];
    pb[(16 + row) * 32 + 16 + m] = a11[r];
  }
}

// K3: out = sum_s part[s] / sum_s Z[s]   (4 slices)
__global__ __launch_bounds__(256) void k3_final(const float* __restrict__ part,
                                                const float* __restrict__ Zpart,
                                                float* __restrict__ out) {
  unsigned int idx4 = blockIdx.x * 256 + threadIdx.x;   // float4 index
  unsigned int h = idx4 / 49152u;
  unsigned int i = (idx4 - h * 49152u) >> 3;
  float z = 0.f;
  #pragma unroll
  for (int s = 0; s < 4; ++s) z += Zpart[s * 24576u + h * N_NODES + i];
  f32x4 p = {0.f, 0.f, 0.f, 0.f};
  const f32x4* P = (const f32x4*)part;
  #pragma unroll
  for (int s = 0; s < 4; ++s) p += P[(size_t)s * 196608u + idx4];
  float rz = 1.0f / z;
  ((f32x4*)out)[idx4] = p * rz;
}

extern "C" void kernel_launch(void* const* d_in, const int* in_sizes, int n_in,
                              void* d_out, int out_size, void* d_ws, size_t ws_size,
                              hipStream_t stream) {
  const float* x = (const float*)d_in[0];
  const int* adj = (const int*)d_in[1];
  const float* W = (const float*)d_in[2];
  const float* a = (const float*)d_in[3];
  float* out = (float*)d_out;

  float* wsf = (float*)d_ws;
  unsigned short* hfF = (unsigned short*)wsf;       // 4*192*2*64*8 bf16 (1.5 MB)
  float* s_src2 = wsf + 393216;                     // 4*6144
  float* s_dst2 = s_src2 + 24576;                   // 4*6144
  float* part   = s_dst2 + 24576;                   // 4 slices * 786432 (12 MB)
  float* Zpart  = part + 4 * 786432;                // 4 slices * 24576

  hipLaunchKernelGGL(k1_feat, dim3(768), dim3(256), 0, stream, x, W, a, hfF, s_src2, s_dst2);
  hipLaunchKernelGGL(k2_attn, dim3(768), dim3(256), 0, stream,
                     adj, hfF, s_src2, s_dst2, Zpart, part);
  hipLaunchKernelGGL(k3_final, dim3(768), dim3(256), 0, stream, part, Zpart, out);
}